// Round 5
// baseline (1444.441 us; speedup 1.0000x reference)
//
#include <hip/hip_runtime.h>

typedef unsigned short u16;
typedef __bf16 bf16x8 __attribute__((ext_vector_type(8)));
typedef float f32x4 __attribute__((ext_vector_type(4)));
typedef unsigned short us8v __attribute__((ext_vector_type(8)));
typedef unsigned short us4v __attribute__((ext_vector_type(4)));

constexpr int NN = 262144;   // nodes
constexpr int NE = 1048576;  // edges
constexpr int NG = 8192;     // graphs
#define SLOPEF 0.1f

__device__ __forceinline__ float lrelu(float v) { return v > 0.f ? v : SLOPEF * v; }

__device__ __forceinline__ u16 f2bf(float f) {
  unsigned u = __builtin_bit_cast(unsigned, f);
  u += 0x7FFFu + ((u >> 16) & 1u);           // RNE
  return (u16)(u >> 16);
}
__device__ __forceinline__ float bf2f(u16 s) {
  return __builtin_bit_cast(float, ((unsigned)s) << 16);
}

// ---------------- device-global scratch ----------------
// NEVER passed as kernel arguments from host code (host sees shadow symbols,
// not device addresses -> GPU page fault; round-3 lesson). Referenced only
// inside device code.
__device__ __align__(256) u16   g_HB[(size_t)NN * 256];     // current h, bf16
__device__ __align__(256) u16   g_AGG[(size_t)NN * 256];    // mean-aggregated h, bf16
__device__ __align__(256) u16   g_WTe[256 * 64];            // embed W^T  [n][k]
__device__ __align__(256) u16   g_WTl[3 * 256 * 512];       // [Wl;Wr]^T per layer [n][k]
__device__ __align__(256) int   g_indptr[NN + 1];
__device__ __align__(256) int   g_cursor[NN];
__device__ __align__(256) int   g_colsrc[NE];
__device__ __align__(256) int   g_bsum[256];
__device__ __align__(256) int   g_boff[256];
__device__ __align__(256) int   g_degi[NN];                 // becomes inv_deg (float) after k_invcur
__device__ __align__(256) float g_pooled[(size_t)NG * 256];

// ---------------- zero fill ----------------
__global__ __launch_bounds__(256) void k_zero_deg() {
  g_degi[blockIdx.x * 256 + threadIdx.x] = 0;
}
__global__ __launch_bounds__(256) void k_zero_pool() {
  ((float4*)g_pooled)[blockIdx.x * 256 + threadIdx.x] = make_float4(0.f, 0.f, 0.f, 0.f);
}

// ---------------- weight transpose + fp32 -> bf16 ----------------
__global__ __launch_bounds__(256) void k_convw(const float* __restrict__ embed_w,
    const float* __restrict__ lin_l_w, const float* __restrict__ lin_r_w) {
  int t = blockIdx.x * 256 + threadIdx.x;
  if (t < 16384) {
    int n = t >> 6, k = t & 63;
    g_WTe[t] = f2bf(embed_w[k * 256 + n]);
  } else {
    int u = t - 16384;
    int l = u >> 17;
    int r = u & 131071;
    int n = r >> 9, k = r & 511;
    float v = (k < 256) ? lin_l_w[(size_t)l * 65536 + k * 256 + n]
                        : lin_r_w[(size_t)l * 65536 + (k - 256) * 256 + n];
    g_WTl[(size_t)l * 131072 + n * 512 + k] = f2bf(v);
  }
}

// ---------------- CSR build ----------------
__global__ __launch_bounds__(256) void k_deg(const int* __restrict__ dst) {
  int e = blockIdx.x * 256 + threadIdx.x;
  atomicAdd(&g_degi[dst[e]], 1);
}

__global__ __launch_bounds__(256) void k_scan1() {
  __shared__ int sm[256];
  int b = blockIdx.x, t = threadIdx.x;
  int4 v = *(const int4*)(g_degi + (size_t)b * 1024 + t * 4);
  int s = v.x + v.y + v.z + v.w;
  sm[t] = s; __syncthreads();
  for (int off = 1; off < 256; off <<= 1) {
    int x = (t >= off) ? sm[t - off] : 0; __syncthreads();
    sm[t] += x; __syncthreads();
  }
  if (t == 255) g_bsum[b] = sm[255];
}

__global__ __launch_bounds__(256) void k_scan2() {
  __shared__ int sm[256];
  int t = threadIdx.x;
  int v = g_bsum[t];
  sm[t] = v; __syncthreads();
  for (int off = 1; off < 256; off <<= 1) {
    int x = (t >= off) ? sm[t - off] : 0; __syncthreads();
    sm[t] += x; __syncthreads();
  }
  g_boff[t] = sm[t] - v;
  if (t == 255) g_indptr[NN] = sm[255];
}

__global__ __launch_bounds__(256) void k_scan3() {
  __shared__ int sm[256];
  int b = blockIdx.x, t = threadIdx.x;
  int4 v = *(const int4*)(g_degi + (size_t)b * 1024 + t * 4);
  int s = v.x + v.y + v.z + v.w;
  sm[t] = s; __syncthreads();
  for (int off = 1; off < 256; off <<= 1) {
    int x = (t >= off) ? sm[t - off] : 0; __syncthreads();
    sm[t] += x; __syncthreads();
  }
  int base = g_boff[b] + sm[t] - s;
  int i0 = b * 1024 + t * 4;
  g_indptr[i0]     = base;
  g_indptr[i0 + 1] = base + v.x;
  g_indptr[i0 + 2] = base + v.x + v.y;
  g_indptr[i0 + 3] = base + v.x + v.y + v.z;
}

// inv_deg aliases g_degi (read int, write float at same index)
__global__ __launch_bounds__(256) void k_invcur() {
  int n = blockIdx.x * 256 + threadIdx.x;
  float inv = 1.0f / fmaxf((float)g_degi[n], 1.0f);
  ((float*)g_degi)[n] = inv;
  g_cursor[n] = g_indptr[n];
}

__global__ __launch_bounds__(256) void k_fill(const int* __restrict__ ei) {
  int e = blockIdx.x * 256 + threadIdx.x;
  int src = ei[e], dst = ei[NE + e];
  int p = atomicAdd(&g_cursor[dst], 1);
  g_colsrc[p] = src;
}

// ---------------- gather-mean: AGG[n] = bf16( inv_deg[n] * sum_{src in N(n)} HB[src] ) ----------------
__global__ __launch_bounds__(256) void k_gather() {
  int n = blockIdx.x * 4 + (threadIdx.x >> 6);
  int lane = threadIdx.x & 63;
  int s = g_indptr[n], e = g_indptr[n + 1];
  float a0 = 0.f, a1 = 0.f, a2 = 0.f, a3 = 0.f;
  for (int i = s; i < e; ++i) {
    int src = g_colsrc[i];
    us4v v = *(const us4v*)(g_HB + (size_t)src * 256 + lane * 4);
    a0 += bf2f(v[0]); a1 += bf2f(v[1]); a2 += bf2f(v[2]); a3 += bf2f(v[3]);
  }
  float w = ((const float*)g_degi)[n];
  us4v o;
  o[0] = f2bf(a0 * w); o[1] = f2bf(a1 * w); o[2] = f2bf(a2 * w); o[3] = f2bf(a3 * w);
  *(us4v*)(g_AGG + (size_t)n * 256 + lane * 4) = o;
}

// ---------------- bf16 MFMA GEMM ----------------
// C[64 x 256] per block -> g_HB (full width => block owns its rows => in-place safe).
// AMODE 0: A = Axf (x fp32 [NN,64], converted to bf16 in staging), WT = g_WTe, KSTEPS=1.
// AMODE 1: A = [g_AGG | g_HB] bf16 (K=512), WT = g_WTl + layer*131072, KSTEPS=8.
// bias is fp32. LDS granule-major: granule g (8 bf16 of k), addr = g*ROWS*16 + row*16.
template<int KSTEPS, int AMODE, bool LEAKY>
__global__ __launch_bounds__(256) void k_gemm(
    const float* __restrict__ Axf, const float* __restrict__ bias, int layer) {
  __shared__ __align__(16) unsigned char As[8192];    // 8 granules x 64 rows x 16B
  __shared__ __align__(16) unsigned char Bs[32768];   // 8 granules x 256 rows x 16B
  constexpr int LDW = AMODE ? 512 : 64;
  const u16* __restrict__ WT = AMODE ? (g_WTl + (size_t)layer * 131072) : g_WTe;
  const int tid = threadIdx.x;
  const int lane = tid & 63;
  const int w = tid >> 6;
  const int wr = w >> 1, wc = w & 1;
  const int m0 = blockIdx.x * 64;
  const int tg = tid & 7, tr = tid >> 3;

  f32x4 acc[2][8];
#pragma unroll
  for (int mi = 0; mi < 2; ++mi)
#pragma unroll
    for (int nj = 0; nj < 8; ++nj) acc[mi][nj] = (f32x4){0.f, 0.f, 0.f, 0.f};

  for (int s = 0; s < KSTEPS; ++s) {
    const int k0 = s * 64;
    us8v areg0, areg1;
    if (AMODE == 0) {
      const float* p0 = Axf + (size_t)(m0 + tr) * 64 + tg * 8;
      const float* p1 = Axf + (size_t)(m0 + tr + 32) * 64 + tg * 8;
      float4 f0 = *(const float4*)p0, f1 = *(const float4*)(p0 + 4);
      float4 g0 = *(const float4*)p1, g1 = *(const float4*)(p1 + 4);
      areg0[0] = f2bf(f0.x); areg0[1] = f2bf(f0.y); areg0[2] = f2bf(f0.z); areg0[3] = f2bf(f0.w);
      areg0[4] = f2bf(f1.x); areg0[5] = f2bf(f1.y); areg0[6] = f2bf(f1.z); areg0[7] = f2bf(f1.w);
      areg1[0] = f2bf(g0.x); areg1[1] = f2bf(g0.y); areg1[2] = f2bf(g0.z); areg1[3] = f2bf(g0.w);
      areg1[4] = f2bf(g1.x); areg1[5] = f2bf(g1.y); areg1[6] = f2bf(g1.z); areg1[7] = f2bf(g1.w);
    } else {
      const u16* src = (k0 < 256) ? (g_AGG + k0) : (g_HB + (k0 - 256));
      areg0 = *(const us8v*)(src + (size_t)(m0 + tr) * 256 + tg * 8);
      areg1 = *(const us8v*)(src + (size_t)(m0 + tr + 32) * 256 + tg * 8);
    }
    us8v breg[8];
#pragma unroll
    for (int it = 0; it < 8; ++it)
      breg[it] = *(const us8v*)(WT + (size_t)(tr + 32 * it) * LDW + k0 + tg * 8);
    __syncthreads();
    *(us8v*)(As + tg * 1024 + tr * 16) = areg0;
    *(us8v*)(As + tg * 1024 + (tr + 32) * 16) = areg1;
#pragma unroll
    for (int it = 0; it < 8; ++it)
      *(us8v*)(Bs + tg * 4096 + (tr + 32 * it) * 16) = breg[it];
    __syncthreads();
#pragma unroll
    for (int ks = 0; ks < 2; ++ks) {
      const int gsel = ks * 4 + (lane >> 4);
      bf16x8 a0 = *(const bf16x8*)(As + gsel * 1024 + (wr * 32 + (lane & 15)) * 16);
      bf16x8 a1 = *(const bf16x8*)(As + gsel * 1024 + (wr * 32 + 16 + (lane & 15)) * 16);
#pragma unroll
      for (int nj = 0; nj < 8; ++nj) {
        bf16x8 b = *(const bf16x8*)(Bs + gsel * 4096 + (wc * 128 + nj * 16 + (lane & 15)) * 16);
        acc[0][nj] = __builtin_amdgcn_mfma_f32_16x16x32_bf16(a0, b, acc[0][nj], 0, 0, 0);
        acc[1][nj] = __builtin_amdgcn_mfma_f32_16x16x32_bf16(a1, b, acc[1][nj], 0, 0, 0);
      }
    }
  }
  // C/D layout: col = lane&15, row = (lane>>4)*4 + reg   [m89-verified]
#pragma unroll
  for (int mi = 0; mi < 2; ++mi)
#pragma unroll
    for (int nj = 0; nj < 8; ++nj) {
      const int col = wc * 128 + nj * 16 + (lane & 15);
      const float bb = bias[col];
#pragma unroll
      for (int j = 0; j < 4; ++j) {
        const int row = m0 + wr * 32 + mi * 16 + (lane >> 4) * 4 + j;
        float v = acc[mi][nj][j] + bb;
        if (LEAKY) v = lrelu(v);
        g_HB[(size_t)row * 256 + col] = f2bf(v);
      }
    }
}

// ---------------- pool (batch sorted) ----------------
__global__ __launch_bounds__(256) void k_pool(const int* __restrict__ batch) {
  int c = threadIdx.x;
  int n0 = blockIdx.x * 64;
  int gprev = batch[n0];
  float acc = 0.f;
  for (int i = 0; i < 64; ++i) {
    int n = n0 + i;
    int g = batch[n];
    if (g != gprev) {
      unsafeAtomicAdd(&g_pooled[(size_t)gprev * 256 + c], acc);
      acc = 0.f; gprev = g;
    }
    acc += bf2f(g_HB[(size_t)n * 256 + c]);
  }
  unsafeAtomicAdd(&g_pooled[(size_t)gprev * 256 + c], acc);
}

// ---------------- head: out[g] = leaky(pooled[g]@W1 + b1) @ w2 + b2  (fp32 I/O) ----------------
__global__ __launch_bounds__(256) void k_head(const float* __restrict__ w1,
    const float* __restrict__ b1, const float* __restrict__ w2, const float* __restrict__ b2,
    float* __restrict__ out) {
  __shared__ float p[256];
  __shared__ float red[256];
  int g = blockIdx.x, c = threadIdx.x;
  p[c] = g_pooled[(size_t)g * 256 + c];
  __syncthreads();
  float acc = b1[c];
#pragma unroll 8
  for (int k = 0; k < 256; ++k) acc = fmaf(p[k], w1[k * 256 + c], acc);
  acc = lrelu(acc) * w2[c];
  red[c] = acc;
  __syncthreads();
  for (int s = 128; s > 0; s >>= 1) {
    if (c < s) red[c] += red[c + s];
    __syncthreads();
  }
  if (c == 0) out[g] = red[0] + b2[0];
}

extern "C" void kernel_launch(void* const* d_in, const int* in_sizes, int n_in,
                              void* d_out, int out_size, void* d_ws, size_t ws_size,
                              hipStream_t stream) {
  const float* x       = (const float*)d_in[0];
  const int*   ei      = (const int*)d_in[1];
  const int*   batch   = (const int*)d_in[2];
  const float* embed_w = (const float*)d_in[3];
  const float* embed_b = (const float*)d_in[4];
  const float* lin_l_w = (const float*)d_in[5];
  const float* lin_l_b = (const float*)d_in[6];
  const float* lin_r_w = (const float*)d_in[7];
  const float* lin1_w  = (const float*)d_in[8];
  const float* lin1_b  = (const float*)d_in[9];
  const float* lin2_w  = (const float*)d_in[10];
  const float* lin2_b  = (const float*)d_in[11];
  float* out = (float*)d_out;
  (void)d_ws; (void)ws_size; (void)in_sizes; (void)n_in; (void)out_size;

  k_zero_deg <<<NN / 256, 256, 0, stream>>>();
  k_zero_pool<<<NG * 256 / (4 * 256), 256, 0, stream>>>();
  k_convw<<<(16384 + 3 * 131072) / 256, 256, 0, stream>>>(embed_w, lin_l_w, lin_r_w);
  k_deg  <<<NE / 256, 256, 0, stream>>>(ei + NE);
  k_scan1<<<256, 256, 0, stream>>>();
  k_scan2<<<1, 256, 0, stream>>>();
  k_scan3<<<256, 256, 0, stream>>>();
  k_invcur<<<NN / 256, 256, 0, stream>>>();
  k_fill <<<NE / 256, 256, 0, stream>>>(ei);

  // embed: HB = bf16(x @ embed_w + embed_b)
  k_gemm<1, 0, false><<<NN / 64, 256, 0, stream>>>(x, embed_b, 0);

  for (int i = 0; i < 3; ++i) {
    k_gather<<<NN / 4, 256, 0, stream>>>();
    const float* bb = lin_l_b + (size_t)i * 256;
    if (i < 2)
      k_gemm<8, 1, true><<<NN / 64, 256, 0, stream>>>(nullptr, bb, i);
    else
      k_gemm<8, 1, false><<<NN / 64, 256, 0, stream>>>(nullptr, bb, i);
  }

  k_pool<<<NN / 64, 256, 0, stream>>>(batch);
  k_head<<<NG, 256, 0, stream>>>(lin1_w, lin1_b, lin2_w, lin2_b, out);
}

// Round 6
// 1249.092 us; speedup vs baseline: 1.1564x; 1.1564x over previous
//
#include <hip/hip_runtime.h>

typedef unsigned short u16;
typedef __bf16 bf16x8 __attribute__((ext_vector_type(8)));
typedef float f32x4 __attribute__((ext_vector_type(4)));
typedef unsigned short us8v __attribute__((ext_vector_type(8)));
typedef unsigned short us4v __attribute__((ext_vector_type(4)));

constexpr int NN = 262144;   // nodes
constexpr int NE = 1048576;  // edges
constexpr int NG = 8192;     // graphs
#define SLOPEF 0.1f

__device__ __forceinline__ float lrelu(float v) { return v > 0.f ? v : SLOPEF * v; }

__device__ __forceinline__ u16 f2bf(float f) {
  unsigned u = __builtin_bit_cast(unsigned, f);
  u += 0x7FFFu + ((u >> 16) & 1u);           // RNE
  return (u16)(u >> 16);
}
__device__ __forceinline__ float bf2f(u16 s) {
  return __builtin_bit_cast(float, ((unsigned)s) << 16);
}

// ---------------- device-global scratch ----------------
// NEVER passed as kernel arguments from host (host sees shadow symbols ->
// GPU page fault; round-3 lesson). Referenced only inside device code.
__device__ __align__(256) u16   g_HB[(size_t)NN * 256];     // current h, bf16
__device__ __align__(256) u16   g_AGG[(size_t)NN * 256];    // mean-aggregated h, bf16
__device__ __align__(256) u16   g_WTe[256 * 64];            // embed W^T  [n][k]
__device__ __align__(256) u16   g_WTl[3 * 256 * 512];       // [Wl;Wr]^T per layer [n][k]
__device__ __align__(256) int   g_indptr[NN + 1];
__device__ __align__(256) int   g_cursor[NN];
__device__ __align__(256) int   g_colsrc[NE];
__device__ __align__(256) int   g_bsum[256];
__device__ __align__(256) int   g_boff[256];
__device__ __align__(256) int   g_degi[NN];                 // becomes inv_deg (float) after k_invcur
__device__ __align__(256) float g_pooled[(size_t)NG * 256];

// ---------------- zero fill ----------------
__global__ __launch_bounds__(256) void k_zero_deg() {
  g_degi[blockIdx.x * 256 + threadIdx.x] = 0;
}
__global__ __launch_bounds__(256) void k_zero_pool() {
  ((float4*)g_pooled)[blockIdx.x * 256 + threadIdx.x] = make_float4(0.f, 0.f, 0.f, 0.f);
}

// ---------------- weight transpose + fp32 -> bf16 ----------------
__global__ __launch_bounds__(256) void k_convw(const float* __restrict__ embed_w,
    const float* __restrict__ lin_l_w, const float* __restrict__ lin_r_w) {
  int t = blockIdx.x * 256 + threadIdx.x;
  if (t < 16384) {
    int n = t >> 6, k = t & 63;
    g_WTe[t] = f2bf(embed_w[k * 256 + n]);
  } else {
    int u = t - 16384;
    int l = u >> 17;
    int r = u & 131071;
    int n = r >> 9, k = r & 511;
    float v = (k < 256) ? lin_l_w[(size_t)l * 65536 + k * 256 + n]
                        : lin_r_w[(size_t)l * 65536 + (k - 256) * 256 + n];
    g_WTl[(size_t)l * 131072 + n * 512 + k] = f2bf(v);
  }
}

// ---------------- CSR build ----------------
__global__ __launch_bounds__(256) void k_deg(const int* __restrict__ dst) {
  int e = blockIdx.x * 256 + threadIdx.x;
  atomicAdd(&g_degi[dst[e]], 1);
}

__global__ __launch_bounds__(256) void k_scan1() {
  __shared__ int sm[256];
  int b = blockIdx.x, t = threadIdx.x;
  int4 v = *(const int4*)(g_degi + (size_t)b * 1024 + t * 4);
  int s = v.x + v.y + v.z + v.w;
  sm[t] = s; __syncthreads();
  for (int off = 1; off < 256; off <<= 1) {
    int x = (t >= off) ? sm[t - off] : 0; __syncthreads();
    sm[t] += x; __syncthreads();
  }
  if (t == 255) g_bsum[b] = sm[255];
}

__global__ __launch_bounds__(256) void k_scan2() {
  __shared__ int sm[256];
  int t = threadIdx.x;
  int v = g_bsum[t];
  sm[t] = v; __syncthreads();
  for (int off = 1; off < 256; off <<= 1) {
    int x = (t >= off) ? sm[t - off] : 0; __syncthreads();
    sm[t] += x; __syncthreads();
  }
  g_boff[t] = sm[t] - v;
  if (t == 255) g_indptr[NN] = sm[255];
}

__global__ __launch_bounds__(256) void k_scan3() {
  __shared__ int sm[256];
  int b = blockIdx.x, t = threadIdx.x;
  int4 v = *(const int4*)(g_degi + (size_t)b * 1024 + t * 4);
  int s = v.x + v.y + v.z + v.w;
  sm[t] = s; __syncthreads();
  for (int off = 1; off < 256; off <<= 1) {
    int x = (t >= off) ? sm[t - off] : 0; __syncthreads();
    sm[t] += x; __syncthreads();
  }
  int base = g_boff[b] + sm[t] - s;
  int i0 = b * 1024 + t * 4;
  g_indptr[i0]     = base;
  g_indptr[i0 + 1] = base + v.x;
  g_indptr[i0 + 2] = base + v.x + v.y;
  g_indptr[i0 + 3] = base + v.x + v.y + v.z;
}

// inv_deg aliases g_degi (read int, write float at same index)
__global__ __launch_bounds__(256) void k_invcur() {
  int n = blockIdx.x * 256 + threadIdx.x;
  float inv = 1.0f / fmaxf((float)g_degi[n], 1.0f);
  ((float*)g_degi)[n] = inv;
  g_cursor[n] = g_indptr[n];
}

__global__ __launch_bounds__(256) void k_fill(const int* __restrict__ ei) {
  int e = blockIdx.x * 256 + threadIdx.x;
  int src = ei[e], dst = ei[NE + e];
  int p = atomicAdd(&g_cursor[dst], 1);
  g_colsrc[p] = src;
}

// ---------------- gather-mean: AGG[n] = bf16( inv_deg[n] * sum_{src in N(n)} HB[src] ) ----------------
// 4-deep unroll: 4 independent row fetches in flight (was 1 -> latency-bound).
__global__ __launch_bounds__(256) void k_gather() {
  int n = blockIdx.x * 4 + (threadIdx.x >> 6);
  int lane = threadIdx.x & 63;
  int s = g_indptr[n], e = g_indptr[n + 1];
  float a0 = 0.f, a1 = 0.f, a2 = 0.f, a3 = 0.f;
  int i = s;
  for (; i + 4 <= e; i += 4) {
    int s0 = g_colsrc[i], s1 = g_colsrc[i + 1], s2 = g_colsrc[i + 2], s3 = g_colsrc[i + 3];
    us4v v0 = *(const us4v*)(g_HB + (size_t)s0 * 256 + lane * 4);
    us4v v1 = *(const us4v*)(g_HB + (size_t)s1 * 256 + lane * 4);
    us4v v2 = *(const us4v*)(g_HB + (size_t)s2 * 256 + lane * 4);
    us4v v3 = *(const us4v*)(g_HB + (size_t)s3 * 256 + lane * 4);
    a0 += bf2f(v0[0]) + bf2f(v1[0]) + bf2f(v2[0]) + bf2f(v3[0]);
    a1 += bf2f(v0[1]) + bf2f(v1[1]) + bf2f(v2[1]) + bf2f(v3[1]);
    a2 += bf2f(v0[2]) + bf2f(v1[2]) + bf2f(v2[2]) + bf2f(v3[2]);
    a3 += bf2f(v0[3]) + bf2f(v1[3]) + bf2f(v2[3]) + bf2f(v3[3]);
  }
  for (; i < e; ++i) {
    int src = g_colsrc[i];
    us4v v = *(const us4v*)(g_HB + (size_t)src * 256 + lane * 4);
    a0 += bf2f(v[0]); a1 += bf2f(v[1]); a2 += bf2f(v[2]); a3 += bf2f(v[3]);
  }
  float w = ((const float*)g_degi)[n];
  us4v o;
  o[0] = f2bf(a0 * w); o[1] = f2bf(a1 * w); o[2] = f2bf(a2 * w); o[3] = f2bf(a3 * w);
  *(us4v*)(g_AGG + (size_t)n * 256 + lane * 4) = o;
}

// ---------------- bf16 MFMA GEMM ----------------
// Block tile 128 M x 256 N, 4 waves (2x2), wave tile 64x128, acc 4x8.
// In-place safe over g_HB: block owns rows [m0,m0+128) and writes full width.
// LDS layout (T2 XOR swizzle): addr(row, g) = row*128 + ((g ^ (row&7))<<4).
//   - staging ds_write_b128: 8 lanes of a row-group cover all 32 banks (was 8-way conflict)
//   - fragment ds_read_b128: 16 rows at fixed g -> 2-way alias = free (m136)
// AMODE 0: A = Axf (x fp32 [NN,64] -> bf16 in staging), WT = g_WTe,  KSTEPS=1.
// AMODE 1: A = [g_AGG | g_HB] bf16 (K=512),  WT = g_WTl + layer*131072, KSTEPS=8.
template<int KSTEPS, int AMODE, bool LEAKY>
__global__ __launch_bounds__(256) void k_gemm(
    const float* __restrict__ Axf, const float* __restrict__ bias, int layer) {
  __shared__ __align__(16) unsigned char As[16384];   // 128 rows x 8 gran x 16B
  __shared__ __align__(16) unsigned char Bs[32768];   // 256 n    x 8 gran x 16B
  constexpr int LDW = AMODE ? 512 : 64;
  const u16* __restrict__ WT = AMODE ? (g_WTl + (size_t)layer * 131072) : g_WTe;
  const int tid = threadIdx.x;
  const int lane = tid & 63;
  const int w = tid >> 6;
  const int wr = w >> 1, wc = w & 1;
  const int m0 = blockIdx.x * 128;
  const int srow = tid >> 1;          // staging row / B col 0..127
  const int sj   = tid & 1;           // granule half (4 granules each)

  f32x4 acc[4][8];
#pragma unroll
  for (int mi = 0; mi < 4; ++mi)
#pragma unroll
    for (int nj = 0; nj < 8; ++nj) acc[mi][nj] = (f32x4){0.f, 0.f, 0.f, 0.f};

  for (int s = 0; s < KSTEPS; ++s) {
    const int k0 = s * 64;
    us8v areg[4], breg[8];
    if (AMODE == 0) {
      const float* p = Axf + (size_t)(m0 + srow) * 64 + sj * 32;
#pragma unroll
      for (int i = 0; i < 4; ++i) {
        float4 f0 = *(const float4*)(p + i * 8);
        float4 f1 = *(const float4*)(p + i * 8 + 4);
        areg[i][0] = f2bf(f0.x); areg[i][1] = f2bf(f0.y);
        areg[i][2] = f2bf(f0.z); areg[i][3] = f2bf(f0.w);
        areg[i][4] = f2bf(f1.x); areg[i][5] = f2bf(f1.y);
        areg[i][6] = f2bf(f1.z); areg[i][7] = f2bf(f1.w);
      }
    } else {
      const u16* srcb = ((k0 < 256) ? (g_AGG + k0) : (g_HB + (k0 - 256)))
                        + (size_t)(m0 + srow) * 256 + sj * 32;
#pragma unroll
      for (int i = 0; i < 4; ++i) areg[i] = *(const us8v*)(srcb + i * 8);
    }
#pragma unroll
    for (int it = 0; it < 2; ++it) {
      const int n = srow + it * 128;
      const u16* srcb = WT + (size_t)n * LDW + k0 + sj * 32;
#pragma unroll
      for (int i = 0; i < 4; ++i) breg[it * 4 + i] = *(const us8v*)(srcb + i * 8);
    }
    __syncthreads();
#pragma unroll
    for (int i = 0; i < 4; ++i) {
      const int g = sj * 4 + i;
      *(us8v*)(As + srow * 128 + ((g ^ (srow & 7)) << 4)) = areg[i];
    }
#pragma unroll
    for (int it = 0; it < 2; ++it) {
      const int n = srow + it * 128;
#pragma unroll
      for (int i = 0; i < 4; ++i) {
        const int g = sj * 4 + i;
        *(us8v*)(Bs + n * 128 + ((g ^ (n & 7)) << 4)) = breg[it * 4 + i];
      }
    }
    __syncthreads();
#pragma unroll
    for (int ks = 0; ks < 2; ++ks) {
      const int gsel = ks * 4 + (lane >> 4);
      const int swz = (gsel ^ (lane & 7)) << 4;
      bf16x8 a[4];
#pragma unroll
      for (int mi = 0; mi < 4; ++mi)
        a[mi] = *(const bf16x8*)(As + (wr * 64 + mi * 16 + (lane & 15)) * 128 + swz);
#pragma unroll
      for (int nj = 0; nj < 8; ++nj) {
        bf16x8 b = *(const bf16x8*)(Bs + (wc * 128 + nj * 16 + (lane & 15)) * 128 + swz);
#pragma unroll
        for (int mi = 0; mi < 4; ++mi)
          acc[mi][nj] = __builtin_amdgcn_mfma_f32_16x16x32_bf16(a[mi], b, acc[mi][nj], 0, 0, 0);
      }
    }
  }
  // C/D layout: col = lane&15, row = (lane>>4)*4 + reg   [m89-verified]
#pragma unroll
  for (int mi = 0; mi < 4; ++mi)
#pragma unroll
    for (int nj = 0; nj < 8; ++nj) {
      const int col = wc * 128 + nj * 16 + (lane & 15);
      const float bb = bias[col];
#pragma unroll
      for (int j = 0; j < 4; ++j) {
        const int row = m0 + wr * 64 + mi * 16 + (lane >> 4) * 4 + j;
        float v = acc[mi][nj][j] + bb;
        if (LEAKY) v = lrelu(v);
        g_HB[(size_t)row * 256 + col] = f2bf(v);
      }
    }
}

// ---------------- pool (batch sorted) ----------------
__global__ __launch_bounds__(256) void k_pool(const int* __restrict__ batch) {
  int c = threadIdx.x;
  int n0 = blockIdx.x * 64;
  int gprev = batch[n0];
  float acc = 0.f;
  for (int i = 0; i < 64; ++i) {
    int n = n0 + i;
    int g = batch[n];
    if (g != gprev) {
      unsafeAtomicAdd(&g_pooled[(size_t)gprev * 256 + c], acc);
      acc = 0.f; gprev = g;
    }
    acc += bf2f(g_HB[(size_t)n * 256 + c]);
  }
  unsafeAtomicAdd(&g_pooled[(size_t)gprev * 256 + c], acc);
}

// ---------------- head: out[g] = leaky(pooled[g]@W1 + b1) @ w2 + b2  (fp32 I/O) ----------------
__global__ __launch_bounds__(256) void k_head(const float* __restrict__ w1,
    const float* __restrict__ b1, const float* __restrict__ w2, const float* __restrict__ b2,
    float* __restrict__ out) {
  __shared__ float p[256];
  __shared__ float red[256];
  int g = blockIdx.x, c = threadIdx.x;
  p[c] = g_pooled[(size_t)g * 256 + c];
  __syncthreads();
  float acc = b1[c];
#pragma unroll 8
  for (int k = 0; k < 256; ++k) acc = fmaf(p[k], w1[k * 256 + c], acc);
  acc = lrelu(acc) * w2[c];
  red[c] = acc;
  __syncthreads();
  for (int s = 128; s > 0; s >>= 1) {
    if (c < s) red[c] += red[c + s];
    __syncthreads();
  }
  if (c == 0) out[g] = red[0] + b2[0];
}

extern "C" void kernel_launch(void* const* d_in, const int* in_sizes, int n_in,
                              void* d_out, int out_size, void* d_ws, size_t ws_size,
                              hipStream_t stream) {
  const float* x       = (const float*)d_in[0];
  const int*   ei      = (const int*)d_in[1];
  const int*   batch   = (const int*)d_in[2];
  const float* embed_w = (const float*)d_in[3];
  const float* embed_b = (const float*)d_in[4];
  const float* lin_l_w = (const float*)d_in[5];
  const float* lin_l_b = (const float*)d_in[6];
  const float* lin_r_w = (const float*)d_in[7];
  const float* lin1_w  = (const float*)d_in[8];
  const float* lin1_b  = (const float*)d_in[9];
  const float* lin2_w  = (const float*)d_in[10];
  const float* lin2_b  = (const float*)d_in[11];
  float* out = (float*)d_out;
  (void)d_ws; (void)ws_size; (void)in_sizes; (void)n_in; (void)out_size;

  k_zero_deg <<<NN / 256, 256, 0, stream>>>();
  k_zero_pool<<<NG * 256 / (4 * 256), 256, 0, stream>>>();
  k_convw<<<(16384 + 3 * 131072) / 256, 256, 0, stream>>>(embed_w, lin_l_w, lin_r_w);
  k_deg  <<<NE / 256, 256, 0, stream>>>(ei + NE);
  k_scan1<<<256, 256, 0, stream>>>();
  k_scan2<<<1, 256, 0, stream>>>();
  k_scan3<<<256, 256, 0, stream>>>();
  k_invcur<<<NN / 256, 256, 0, stream>>>();
  k_fill <<<NE / 256, 256, 0, stream>>>(ei);

  // embed: HB = bf16(x @ embed_w + embed_b)
  k_gemm<1, 0, false><<<NN / 128, 256, 0, stream>>>(x, embed_b, 0);

  for (int i = 0; i < 3; ++i) {
    k_gather<<<NN / 4, 256, 0, stream>>>();
    const float* bb = lin_l_b + (size_t)i * 256;
    if (i < 2)
      k_gemm<8, 1, true><<<NN / 128, 256, 0, stream>>>(nullptr, bb, i);
    else
      k_gemm<8, 1, false><<<NN / 128, 256, 0, stream>>>(nullptr, bb, i);
  }

  k_pool<<<NN / 64, 256, 0, stream>>>(batch);
  k_head<<<NG, 256, 0, stream>>>(lin1_w, lin1_b, lin2_w, lin2_b, out);
}

// Round 7
// 1232.087 us; speedup vs baseline: 1.1724x; 1.0138x over previous
//
#include <hip/hip_runtime.h>

typedef unsigned short u16;
typedef __bf16 bf16x8 __attribute__((ext_vector_type(8)));
typedef float f32x4 __attribute__((ext_vector_type(4)));
typedef unsigned short us8v __attribute__((ext_vector_type(8)));
typedef unsigned short us4v __attribute__((ext_vector_type(4)));

constexpr int NN = 262144;   // nodes
constexpr int NE = 1048576;  // edges
constexpr int NG = 8192;     // graphs
#define SLOPEF 0.1f

__device__ __forceinline__ float lrelu(float v) { return v > 0.f ? v : SLOPEF * v; }

__device__ __forceinline__ u16 f2bf(float f) {
  unsigned u = __builtin_bit_cast(unsigned, f);
  u += 0x7FFFu + ((u >> 16) & 1u);           // RNE
  return (u16)(u >> 16);
}
__device__ __forceinline__ float bf2f(u16 s) {
  return __builtin_bit_cast(float, ((unsigned)s) << 16);
}

// async 16B global -> LDS DMA (lane i of the wave writes ldsbase + i*16)
__device__ __forceinline__ void gload_lds16(const u16* g, unsigned char* l) {
  __builtin_amdgcn_global_load_lds(
      (const __attribute__((address_space(1))) unsigned int*)g,
      (__attribute__((address_space(3))) unsigned int*)l, 16, 0, 0);
}

// ---------------- device-global scratch ----------------
// NEVER passed as kernel arguments from host (host sees shadow symbols ->
// GPU page fault; round-3 lesson). Referenced only inside device code.
__device__ __align__(256) u16   g_HB[(size_t)NN * 256];     // current h, bf16
__device__ __align__(256) u16   g_AGG[(size_t)NN * 256];    // mean-aggregated h, bf16
__device__ __align__(256) u16   g_WTe[256 * 64];            // embed W^T  [n][k]
__device__ __align__(256) u16   g_WTl[3 * 256 * 512];       // [Wl;Wr]^T per layer [n][k]
__device__ __align__(256) int   g_indptr[NN + 1];
__device__ __align__(256) int   g_cursor[NN];
__device__ __align__(256) int   g_colsrc[NE];
__device__ __align__(256) int   g_bsum[256];
__device__ __align__(256) int   g_boff[256];
__device__ __align__(256) int   g_degi[NN];                 // becomes inv_deg (float) after k_invcur
__device__ __align__(256) float g_pooled[(size_t)NG * 256];

// ---------------- zero fill ----------------
__global__ __launch_bounds__(256) void k_zero_deg() {
  g_degi[blockIdx.x * 256 + threadIdx.x] = 0;
}
__global__ __launch_bounds__(256) void k_zero_pool() {
  ((float4*)g_pooled)[blockIdx.x * 256 + threadIdx.x] = make_float4(0.f, 0.f, 0.f, 0.f);
}

// ---------------- weight transpose + fp32 -> bf16 ----------------
__global__ __launch_bounds__(256) void k_convw(const float* __restrict__ embed_w,
    const float* __restrict__ lin_l_w, const float* __restrict__ lin_r_w) {
  int t = blockIdx.x * 256 + threadIdx.x;
  if (t < 16384) {
    int n = t >> 6, k = t & 63;
    g_WTe[t] = f2bf(embed_w[k * 256 + n]);
  } else {
    int u = t - 16384;
    int l = u >> 17;
    int r = u & 131071;
    int n = r >> 9, k = r & 511;
    float v = (k < 256) ? lin_l_w[(size_t)l * 65536 + k * 256 + n]
                        : lin_r_w[(size_t)l * 65536 + (k - 256) * 256 + n];
    g_WTl[(size_t)l * 131072 + n * 512 + k] = f2bf(v);
  }
}

// ---------------- CSR build ----------------
__global__ __launch_bounds__(256) void k_deg(const int* __restrict__ dst) {
  int e = blockIdx.x * 256 + threadIdx.x;
  atomicAdd(&g_degi[dst[e]], 1);
}

__global__ __launch_bounds__(256) void k_scan1() {
  __shared__ int sm[256];
  int b = blockIdx.x, t = threadIdx.x;
  int4 v = *(const int4*)(g_degi + (size_t)b * 1024 + t * 4);
  int s = v.x + v.y + v.z + v.w;
  sm[t] = s; __syncthreads();
  for (int off = 1; off < 256; off <<= 1) {
    int x = (t >= off) ? sm[t - off] : 0; __syncthreads();
    sm[t] += x; __syncthreads();
  }
  if (t == 255) g_bsum[b] = sm[255];
}

__global__ __launch_bounds__(256) void k_scan2() {
  __shared__ int sm[256];
  int t = threadIdx.x;
  int v = g_bsum[t];
  sm[t] = v; __syncthreads();
  for (int off = 1; off < 256; off <<= 1) {
    int x = (t >= off) ? sm[t - off] : 0; __syncthreads();
    sm[t] += x; __syncthreads();
  }
  g_boff[t] = sm[t] - v;
  if (t == 255) g_indptr[NN] = sm[255];
}

__global__ __launch_bounds__(256) void k_scan3() {
  __shared__ int sm[256];
  int b = blockIdx.x, t = threadIdx.x;
  int4 v = *(const int4*)(g_degi + (size_t)b * 1024 + t * 4);
  int s = v.x + v.y + v.z + v.w;
  sm[t] = s; __syncthreads();
  for (int off = 1; off < 256; off <<= 1) {
    int x = (t >= off) ? sm[t - off] : 0; __syncthreads();
    sm[t] += x; __syncthreads();
  }
  int base = g_boff[b] + sm[t] - s;
  int i0 = b * 1024 + t * 4;
  g_indptr[i0]     = base;
  g_indptr[i0 + 1] = base + v.x;
  g_indptr[i0 + 2] = base + v.x + v.y;
  g_indptr[i0 + 3] = base + v.x + v.y + v.z;
}

// inv_deg aliases g_degi (read int, write float at same index)
__global__ __launch_bounds__(256) void k_invcur() {
  int n = blockIdx.x * 256 + threadIdx.x;
  float inv = 1.0f / fmaxf((float)g_degi[n], 1.0f);
  ((float*)g_degi)[n] = inv;
  g_cursor[n] = g_indptr[n];
}

__global__ __launch_bounds__(256) void k_fill(const int* __restrict__ ei) {
  int e = blockIdx.x * 256 + threadIdx.x;
  int src = ei[e], dst = ei[NE + e];
  int p = atomicAdd(&g_cursor[dst], 1);
  g_colsrc[p] = src;
}

// ---------------- gather-mean: AGG[n] = bf16( inv_deg[n] * sum_{src in N(n)} HB[src] ) ----------------
__global__ __launch_bounds__(256) void k_gather() {
  int n = blockIdx.x * 4 + (threadIdx.x >> 6);
  int lane = threadIdx.x & 63;
  int s = g_indptr[n], e = g_indptr[n + 1];
  float a0 = 0.f, a1 = 0.f, a2 = 0.f, a3 = 0.f;
  int i = s;
  for (; i + 4 <= e; i += 4) {
    int s0 = g_colsrc[i], s1 = g_colsrc[i + 1], s2 = g_colsrc[i + 2], s3 = g_colsrc[i + 3];
    us4v v0 = *(const us4v*)(g_HB + (size_t)s0 * 256 + lane * 4);
    us4v v1 = *(const us4v*)(g_HB + (size_t)s1 * 256 + lane * 4);
    us4v v2 = *(const us4v*)(g_HB + (size_t)s2 * 256 + lane * 4);
    us4v v3 = *(const us4v*)(g_HB + (size_t)s3 * 256 + lane * 4);
    a0 += bf2f(v0[0]) + bf2f(v1[0]) + bf2f(v2[0]) + bf2f(v3[0]);
    a1 += bf2f(v0[1]) + bf2f(v1[1]) + bf2f(v2[1]) + bf2f(v3[1]);
    a2 += bf2f(v0[2]) + bf2f(v1[2]) + bf2f(v2[2]) + bf2f(v3[2]);
    a3 += bf2f(v0[3]) + bf2f(v1[3]) + bf2f(v2[3]) + bf2f(v3[3]);
  }
  for (; i < e; ++i) {
    int src = g_colsrc[i];
    us4v v = *(const us4v*)(g_HB + (size_t)src * 256 + lane * 4);
    a0 += bf2f(v[0]); a1 += bf2f(v[1]); a2 += bf2f(v[2]); a3 += bf2f(v[3]);
  }
  float w = ((const float*)g_degi)[n];
  us4v o;
  o[0] = f2bf(a0 * w); o[1] = f2bf(a1 * w); o[2] = f2bf(a2 * w); o[3] = f2bf(a3 * w);
  *(us4v*)(g_AGG + (size_t)n * 256 + lane * 4) = o;
}

// ---------------- bf16 MFMA GEMM ----------------
// Block tile 128 M x 256 N, 4 waves (2x2), wave tile 64x128, acc 4x8.
// In-place safe over g_HB: block owns rows [m0,m0+128) and writes full width.
// LDS CONTENT (both modes): addr(row, g) = row*128 + ((g ^ (row&7))<<4)   [round-6 verified]
// AMODE 1 staging = global_load_lds DMA with PRE-SWIZZLED global source:
//   chunk c (1KB) covers rows c*8+(lane>>3), slot lane&7; lane fetches
//   granule gX = (lane&7)^(lane>>3) of its row -> linear LDS write == swizzled content.
// AMODE 0 (x fp32 -> bf16 convert) keeps reg staging with swizzled ds_write.
template<int KSTEPS, int AMODE, bool LEAKY>
__global__ __launch_bounds__(256) void k_gemm(
    const float* __restrict__ Axf, const float* __restrict__ bias, int layer) {
  __shared__ __align__(16) unsigned char As[16384];   // 128 rows x 8 gran x 16B
  __shared__ __align__(16) unsigned char Bs[32768];   // 256 n    x 8 gran x 16B
  const u16* __restrict__ WT = AMODE ? (g_WTl + (size_t)layer * 131072) : g_WTe;
  const int tid = threadIdx.x;
  const int lane = tid & 63;
  const int w = tid >> 6;
  const int wr = w >> 1, wc = w & 1;
  const int m0 = blockIdx.x * 128;
  // DMA staging lane constants
  const int r8 = lane >> 3;              // row-in-chunk
  const int s8 = lane & 7;               // slot
  const int gX = s8 ^ r8;                // granule to fetch (pre-swizzle)
  // AMODE0 reg-staging constants
  const int srow = tid >> 1;
  const int sj   = tid & 1;

  f32x4 acc[4][8];
#pragma unroll
  for (int mi = 0; mi < 4; ++mi)
#pragma unroll
    for (int nj = 0; nj < 8; ++nj) acc[mi][nj] = (f32x4){0.f, 0.f, 0.f, 0.f};

  for (int s = 0; s < KSTEPS; ++s) {
    const int k0 = s * 64;
    if (AMODE == 0) {
      // ---- reg staging (fp32 -> bf16), swizzled ds_write; KSTEPS==1 here ----
      us8v areg[4], breg[8];
      const float* p = Axf + (size_t)(m0 + srow) * 64 + sj * 32;
#pragma unroll
      for (int i = 0; i < 4; ++i) {
        float4 f0 = *(const float4*)(p + i * 8);
        float4 f1 = *(const float4*)(p + i * 8 + 4);
        areg[i][0] = f2bf(f0.x); areg[i][1] = f2bf(f0.y);
        areg[i][2] = f2bf(f0.z); areg[i][3] = f2bf(f0.w);
        areg[i][4] = f2bf(f1.x); areg[i][5] = f2bf(f1.y);
        areg[i][6] = f2bf(f1.z); areg[i][7] = f2bf(f1.w);
      }
#pragma unroll
      for (int it = 0; it < 2; ++it) {
        const int n = srow + it * 128;
        const u16* srcb = WT + (size_t)n * 64 + k0 + sj * 32;
#pragma unroll
        for (int i = 0; i < 4; ++i) breg[it * 4 + i] = *(const us8v*)(srcb + i * 8);
      }
#pragma unroll
      for (int i = 0; i < 4; ++i) {
        const int g = sj * 4 + i;
        *(us8v*)(As + srow * 128 + ((g ^ (srow & 7)) << 4)) = areg[i];
      }
#pragma unroll
      for (int it = 0; it < 2; ++it) {
        const int n = srow + it * 128;
#pragma unroll
        for (int i = 0; i < 4; ++i) {
          const int g = sj * 4 + i;
          *(us8v*)(Bs + n * 128 + ((g ^ (n & 7)) << 4)) = breg[it * 4 + i];
        }
      }
    } else {
      // ---- async DMA staging, pre-swizzled source ----
      const u16* abase = (k0 < 256) ? (g_AGG + k0) : (g_HB + (k0 - 256));
#pragma unroll
      for (int j = 0; j < 4; ++j) {
        const int c = w * 4 + j;                                   // A chunk 0..15
        const u16* gp = abase + (size_t)(m0 + c * 8 + r8) * 256 + gX * 8;
        gload_lds16(gp, As + c * 1024);
      }
#pragma unroll
      for (int j = 0; j < 8; ++j) {
        const int c = w * 8 + j;                                   // B chunk 0..31
        const u16* gp = WT + (size_t)(c * 8 + r8) * 512 + k0 + gX * 8;
        gload_lds16(gp, Bs + c * 1024);
      }
    }
    __syncthreads();   // drains vmcnt (DMA complete) + lgkmcnt, all waves staged
#pragma unroll
    for (int ks = 0; ks < 2; ++ks) {
      const int gsel = ks * 4 + (lane >> 4);
      const int swz = (gsel ^ (lane & 7)) << 4;
      bf16x8 a[4];
#pragma unroll
      for (int mi = 0; mi < 4; ++mi)
        a[mi] = *(const bf16x8*)(As + (wr * 64 + mi * 16 + (lane & 15)) * 128 + swz);
#pragma unroll
      for (int nj = 0; nj < 8; ++nj) {
        bf16x8 b = *(const bf16x8*)(Bs + (wc * 128 + nj * 16 + (lane & 15)) * 128 + swz);
#pragma unroll
        for (int mi = 0; mi < 4; ++mi)
          acc[mi][nj] = __builtin_amdgcn_mfma_f32_16x16x32_bf16(a[mi], b, acc[mi][nj], 0, 0, 0);
      }
    }
    if (s + 1 < KSTEPS) __syncthreads();   // protect LDS before next stage
  }
  // C/D layout: col = lane&15, row = (lane>>4)*4 + reg   [m89-verified]
#pragma unroll
  for (int mi = 0; mi < 4; ++mi)
#pragma unroll
    for (int nj = 0; nj < 8; ++nj) {
      const int col = wc * 128 + nj * 16 + (lane & 15);
      const float bb = bias[col];
#pragma unroll
      for (int j = 0; j < 4; ++j) {
        const int row = m0 + wr * 64 + mi * 16 + (lane >> 4) * 4 + j;
        float v = acc[mi][nj][j] + bb;
        if (LEAKY) v = lrelu(v);
        g_HB[(size_t)row * 256 + col] = f2bf(v);
      }
    }
}

// ---------------- pool (batch sorted) ----------------
__global__ __launch_bounds__(256) void k_pool(const int* __restrict__ batch) {
  int c = threadIdx.x;
  int n0 = blockIdx.x * 64;
  int gprev = batch[n0];
  float acc = 0.f;
  for (int i = 0; i < 64; ++i) {
    int n = n0 + i;
    int g = batch[n];
    if (g != gprev) {
      unsafeAtomicAdd(&g_pooled[(size_t)gprev * 256 + c], acc);
      acc = 0.f; gprev = g;
    }
    acc += bf2f(g_HB[(size_t)n * 256 + c]);
  }
  unsafeAtomicAdd(&g_pooled[(size_t)gprev * 256 + c], acc);
}

// ---------------- head: out[g] = leaky(pooled[g]@W1 + b1) @ w2 + b2  (fp32 I/O) ----------------
__global__ __launch_bounds__(256) void k_head(const float* __restrict__ w1,
    const float* __restrict__ b1, const float* __restrict__ w2, const float* __restrict__ b2,
    float* __restrict__ out) {
  __shared__ float p[256];
  __shared__ float red[256];
  int g = blockIdx.x, c = threadIdx.x;
  p[c] = g_pooled[(size_t)g * 256 + c];
  __syncthreads();
  float acc = b1[c];
#pragma unroll 8
  for (int k = 0; k < 256; ++k) acc = fmaf(p[k], w1[k * 256 + c], acc);
  acc = lrelu(acc) * w2[c];
  red[c] = acc;
  __syncthreads();
  for (int s = 128; s > 0; s >>= 1) {
    if (c < s) red[c] += red[c + s];
    __syncthreads();
  }
  if (c == 0) out[g] = red[0] + b2[0];
}

extern "C" void kernel_launch(void* const* d_in, const int* in_sizes, int n_in,
                              void* d_out, int out_size, void* d_ws, size_t ws_size,
                              hipStream_t stream) {
  const float* x       = (const float*)d_in[0];
  const int*   ei      = (const int*)d_in[1];
  const int*   batch   = (const int*)d_in[2];
  const float* embed_w = (const float*)d_in[3];
  const float* embed_b = (const float*)d_in[4];
  const float* lin_l_w = (const float*)d_in[5];
  const float* lin_l_b = (const float*)d_in[6];
  const float* lin_r_w = (const float*)d_in[7];
  const float* lin1_w  = (const float*)d_in[8];
  const float* lin1_b  = (const float*)d_in[9];
  const float* lin2_w  = (const float*)d_in[10];
  const float* lin2_b  = (const float*)d_in[11];
  float* out = (float*)d_out;
  (void)d_ws; (void)ws_size; (void)in_sizes; (void)n_in; (void)out_size;

  k_zero_deg <<<NN / 256, 256, 0, stream>>>();
  k_zero_pool<<<NG * 256 / (4 * 256), 256, 0, stream>>>();
  k_convw<<<(16384 + 3 * 131072) / 256, 256, 0, stream>>>(embed_w, lin_l_w, lin_r_w);
  k_deg  <<<NE / 256, 256, 0, stream>>>(ei + NE);
  k_scan1<<<256, 256, 0, stream>>>();
  k_scan2<<<1, 256, 0, stream>>>();
  k_scan3<<<256, 256, 0, stream>>>();
  k_invcur<<<NN / 256, 256, 0, stream>>>();
  k_fill <<<NE / 256, 256, 0, stream>>>(ei);

  // embed: HB = bf16(x @ embed_w + embed_b)
  k_gemm<1, 0, false><<<NN / 128, 256, 0, stream>>>(x, embed_b, 0);

  for (int i = 0; i < 3; ++i) {
    k_gather<<<NN / 4, 256, 0, stream>>>();
    const float* bb = lin_l_b + (size_t)i * 256;
    if (i < 2)
      k_gemm<8, 1, true><<<NN / 128, 256, 0, stream>>>(nullptr, bb, i);
    else
      k_gemm<8, 1, false><<<NN / 128, 256, 0, stream>>>(nullptr, bb, i);
  }

  k_pool<<<NN / 64, 256, 0, stream>>>(batch);
  k_head<<<NG, 256, 0, stream>>>(lin1_w, lin1_b, lin2_w, lin2_b, out);
}